// Round 11
// baseline (85.703 us; speedup 1.0000x reference)
//
#include <hip/hip_runtime.h>
#include <math.h>

#define N_ATOMS  50000
#define N_NBRS   32
#define N_GAUSS  25
#define RCUT     5.0f
#define TT       192       // nearest-table nodes, spacing RCUT/191
#define TROWS    32
#define NTB      6         // 192/32 table-build blocks
#define MAXZ     100
#define NT32     1563      // ceil(50000/32) 32-atom chunks
#define ABLOCKS  512       // persistent cfconv blocks (2 per CU)
#define PI_F     3.14159265358979323846f

typedef unsigned int   uint_t;
typedef unsigned short ushort_t;
typedef _Float16 f16;
typedef f16   f16x2 __attribute__((ext_vector_type(2)));
typedef f16   f16x4 __attribute__((ext_vector_type(4)));
typedef f16   f16x8 __attribute__((ext_vector_type(8)));
typedef float f32x4 __attribute__((ext_vector_type(4)));

// fast shifted softplus: max(x,0) + log(0.5 + 0.5*exp(-|x|))
__device__ __forceinline__ float ssp(float x) {
  return fmaxf(x, 0.0f) + __logf(fmaf(0.5f, __expf(-fabsf(x)), 0.5f));
}
__device__ __forceinline__ f16x2 bch(uint_t u) {
  return __builtin_bit_cast(f16x2, u);
}
__device__ __forceinline__ uint_t hcb(f16x2 v) {
  return __builtin_bit_cast(uint_t, v);
}
// swizzled element offset into a [16][128] f16 LDS tile
__device__ __forceinline__ int swz(int m, int e) {
  return m * 128 + ((((e >> 3) ^ m) & 15) << 3) + (e & 7);
}

// ---- prep: blocks [0,NTB) build nearest table; blocks [NTB,NTB+64) transposes+ytab
__global__ void __launch_bounds__(256, 2)
prep_all_kernel(const float* __restrict__ fw1,
                const float* __restrict__ fb1,
                const float* __restrict__ fw2,
                const float* __restrict__ fb2,
                const float* __restrict__ w1,
                const float* __restrict__ w2,
                const float* __restrict__ mw1,
                const float* __restrict__ embed,
                const float* __restrict__ in2f,
                f16* __restrict__ tabh,
                f16* __restrict__ ytab,
                f16* __restrict__ w1ht,
                f16* __restrict__ w2ht,
                f16* __restrict__ mw1ht,
                float* __restrict__ out) {
  const int tid = threadIdx.x;
  const int bid = blockIdx.x;
  if (bid == 0 && tid == 0) out[0] = 0.0f;   // re-zero accumulator every launch

  __shared__ float sW2[128 * 128];       // 64 KB
  __shared__ float sH[TROWS][128];       // 16 KB

  if (bid < NTB) {
    const int i0 = bid * TROWS;
    #pragma unroll
    for (int t = 0; t < 16; ++t) {
      const int e = tid + t * 256;
      ((float4*)sW2)[e] = ((const float4*)fw2)[e];
    }
    // phase 1: H[row][f] = ssp(gauss(r_row) . fw1[:,f] + fb1[f])
    {
      const int f  = tid & 127;
      const int rh = (tid >> 7) * (TROWS / 2);
      const float delta = RCUT / (float)(N_GAUSS - 1);
      const float coeff = -0.5f / (delta * delta);
      const float b1v = fb1[f];
      for (int j = 0; j < TROWS / 2; ++j) {
        const float r = (float)(i0 + rh + j) * (RCUT / 191.0f);
        float h = b1v;
        #pragma unroll
        for (int g = 0; g < N_GAUSS; ++g) {
          const float d = r - (float)g * delta;
          h = fmaf(__expf(coeff * d * d), fw1[g * 128 + f], h);
        }
        sH[rh + j][f] = ssp(h);
      }
    }
    __syncthreads();
    // phase 2: tab[row][c] = H[row][:] @ fw2[:,c] + fb2[c]
    {
      const int c0 = (tid & 31) * 4;
      const int rg = (tid >> 5) * 4;
      f32x4 acc[4];
      const float4 bv = *(const float4*)&fb2[c0];
      #pragma unroll
      for (int j = 0; j < 4; ++j) acc[j] = (f32x4){bv.x, bv.y, bv.z, bv.w};
      for (int k = 0; k < 128; ++k) {
        const float4 wv = *(const float4*)&sW2[k * 128 + c0];
        #pragma unroll
        for (int j = 0; j < 4; ++j) {
          const float hv = sH[rg + j][k];
          acc[j][0] = fmaf(hv, wv.x, acc[j][0]);
          acc[j][1] = fmaf(hv, wv.y, acc[j][1]);
          acc[j][2] = fmaf(hv, wv.z, acc[j][2]);
          acc[j][3] = fmaf(hv, wv.w, acc[j][3]);
        }
      }
      #pragma unroll
      for (int j = 0; j < 4; ++j) {
        const int i = i0 + rg + j;
        const float r = (float)i * (RCUT / 191.0f);
        const float fc = (r < RCUT) ? 0.5f * (__cosf(r * PI_F / RCUT) + 1.0f) : 0.0f;
        f16x4 o;
        #pragma unroll
        for (int c = 0; c < 4; ++c) o[c] = (f16)(acc[j][c] * fc);
        *(f16x4*)&tabh[i * 128 + c0] = o;
      }
    }
  } else {
    const int cc = (bid - NTB) * 2 + (tid >> 7);
    const int i  = tid & 127;
    w1ht[cc * 128 + i] = (f16)w1[i * 128 + cc];
    w2ht[cc * 128 + i] = (f16)w2[i * 128 + cc];
    if (cc < 64) mw1ht[cc * 128 + i] = (f16)mw1[i * 64 + cc];
    float* xs = &sH[0][0] + (tid >> 7) * 128;
    xs[i] = (cc < MAXZ) ? embed[cc * 128 + i] : 0.0f;
    __syncthreads();
    if (cc < MAXZ) {
      float acc = 0.0f;
      for (int j = 0; j < 128; j += 4) {
        const float4 xv = *reinterpret_cast<const float4*>(&xs[j]);
        acc = fmaf(xv.x, in2f[(j + 0) * 128 + i], acc);
        acc = fmaf(xv.y, in2f[(j + 1) * 128 + i], acc);
        acc = fmaf(xv.z, in2f[(j + 2) * 128 + i], acc);
        acc = fmaf(xv.w, in2f[(j + 3) * 128 + i], acc);
      }
      ytab[cc * 128 + i] = (f16)acc;
    }
  }
}

// ---- kernel A: cfconv only. Persistent 512-thread blocks, quarter-wave = atom,
//      lane = 8 channels, nearest table + ytab LDS-resident, 2 barriers/chunk.
__global__ void __launch_bounds__(512, 4)
cfconv_kernel(const float* __restrict__ dR,
              const int* __restrict__ Z,
              const int* __restrict__ nbr,
              const f16* __restrict__ tabh,
              const f16* __restrict__ ytab,
              f16* __restrict__ agg) {
  const int tid = threadIdx.x;
  __shared__ __align__(16) f16    sW[TT * 128];     // 48 KB
  __shared__ __align__(16) f16    sYT[MAXZ * 128];  // 25.6 KB
  __shared__ __align__(16) uint_t s_pk[1024];       // 4 KB: i0 | (z<<8)

  for (int e = tid; e < TT * 16; e += 512)   ((uint4*)sW)[e]  = ((const uint4*)tabh)[e];
  for (int e = tid; e < MAXZ * 16; e += 512) ((uint4*)sYT)[e] = ((const uint4*)ytab)[e];

  const int w  = tid >> 6;        // wave 0..7
  const int l  = tid & 63;
  const int q  = l >> 4;          // quarter = atom within wave's group
  const int cq = l & 15;          // lane -> channels 8cq..8cq+7
  const int m  = w * 4 + q;       // atom 0..31 within chunk
  const char* wb = (const char*)sW  + cq * 16;
  const char* yb = (const char*)sYT + cq * 16;

  for (int tile = blockIdx.x; tile < NT32; tile += ABLOCKS) {
    const int a0 = tile * 32;
    __syncthreads();   // previous chunk's s_pk reads done (also covers table staging)
    #pragma unroll
    for (int t0 = 0; t0 < 2; ++t0) {
      const int t = tid + t0 * 512;
      const int pidx = a0 * N_NBRS + t;
      if (pidx < N_ATOMS * N_NBRS) {
        const float r = dR[pidx];
        const int  nb = nbr[pidx];
        int i0 = (int)(r * (191.0f / RCUT) + 0.5f);
        i0 = min(i0, 191);
        s_pk[t] = (uint_t)i0 | ((uint_t)Z[nb] << 8);
      }
    }
    __syncthreads();

    const int a = a0 + m;
    if (a < N_ATOMS) {
      f16x2 acc[4];
      #pragma unroll
      for (int c = 0; c < 4; ++c) acc[c] = (f16x2)0;

      uint4 twA[4], ytA[4], twB[4], ytB[4];

#define IG(BK, g) { \
    _Pragma("unroll") \
    for (int d = 0; d < 4; ++d) { \
      const uint_t pk = s_pk[m * N_NBRS + (g) * 4 + d]; \
      tw##BK[d] = *(const uint4*)(wb + ((pk & 0xFFu) << 8)); \
      yt##BK[d] = *(const uint4*)(yb + ((pk >> 8) << 8)); \
    } }

#define CG(BK) { \
    _Pragma("unroll") \
    for (int d = 0; d < 4; ++d) { \
      acc[0] += bch(tw##BK[d].x) * bch(yt##BK[d].x); \
      acc[1] += bch(tw##BK[d].y) * bch(yt##BK[d].y); \
      acc[2] += bch(tw##BK[d].z) * bch(yt##BK[d].z); \
      acc[3] += bch(tw##BK[d].w) * bch(yt##BK[d].w); \
    } }

      IG(A, 0) IG(B, 1)
      CG(A) IG(A, 2)
      CG(B) IG(B, 3)
      CG(A) IG(A, 4)
      CG(B) IG(B, 5)
      CG(A) IG(A, 6)
      CG(B) IG(B, 7)
      CG(A)
      CG(B)
#undef IG
#undef CG

      uint4 o;
      o.x = hcb(acc[0]); o.y = hcb(acc[1]); o.z = hcb(acc[2]); o.w = hcb(acc[3]);
      *(uint4*)&agg[(size_t)a * 128 + cq * 8] = o;
    }
  }
}

// ---- kernel B: dense pipeline per 16-atom block (f2out x2 + residual + MLP + sum)
__global__ void __launch_bounds__(256, 4)
dense_kernel(const int* __restrict__ Z,
             const float* __restrict__ embed,
             const f16* __restrict__ agg,
             const f16* __restrict__ w1ht, const float* __restrict__ b1,
             const f16* __restrict__ w2ht, const float* __restrict__ b2,
             const f16* __restrict__ mw1ht, const float* __restrict__ mb1,
             const float* __restrict__ mw2, const float* __restrict__ mb2,
             float* __restrict__ out) {
  const int tid = threadIdx.x;
  const int wv  = tid >> 6;
  const int l   = tid & 63;
  const int a0  = blockIdx.x * 16;
  __shared__ __align__(16) f16 sA[16 * 128];
  __shared__ __align__(16) f16 sB[16 * 128];
  __shared__ int   sZ[16];
  __shared__ float sRed[4];

  // stage agg tile -> sA (swizzled write, coalesced read)
  {
    const int mm = tid >> 4, cc = tid & 15;
    const uint4 v = ((const uint4*)agg)[a0 * 16 + tid];
    *(uint4*)&sA[mm * 128 + (((cc ^ mm) & 15) << 3)] = v;
  }
  if (tid < 16) sZ[tid] = Z[a0 + tid];
  __syncthreads();

  const int rc = l & 15;
  const int qk = l >> 4;
#define AFRAG(SRC, k0) (*(const f16x8*)&SRC[rc * 128 + (((((k0) >> 3) + qk) ^ rc) & 15) * 8])

  // f2out layer 1: wave covers cols wv*32..+31
  f32x4 dacc[2];
  #pragma unroll
  for (int t = 0; t < 2; ++t) {
    const float b = b1[wv * 32 + t * 16 + rc];
    dacc[t] = (f32x4){b, b, b, b};
  }
  #pragma unroll
  for (int k0 = 0; k0 < 128; k0 += 32) {
    const f16x8 af = AFRAG(sA, k0);
    #pragma unroll
    for (int t = 0; t < 2; ++t) {
      const int c = wv * 32 + t * 16 + rc;
      const f16x8 bf = *(const f16x8*)&w1ht[c * 128 + k0 + qk * 8];
      dacc[t] = __builtin_amdgcn_mfma_f32_16x16x32_f16(af, bf, dacc[t], 0, 0, 0);
    }
  }
  #pragma unroll
  for (int t = 0; t < 2; ++t) {
    const int c = wv * 32 + t * 16 + rc;
    #pragma unroll
    for (int r = 0; r < 4; ++r) {
      sB[swz(qk * 4 + r, c)] = (f16)ssp(dacc[t][r]);
    }
  }
  __syncthreads();

  // f2out layer 2 + residual -> sA
  #pragma unroll
  for (int t = 0; t < 2; ++t) {
    const float b = b2[wv * 32 + t * 16 + rc];
    dacc[t] = (f32x4){b, b, b, b};
  }
  #pragma unroll
  for (int k0 = 0; k0 < 128; k0 += 32) {
    const f16x8 af = AFRAG(sB, k0);
    #pragma unroll
    for (int t = 0; t < 2; ++t) {
      const int c = wv * 32 + t * 16 + rc;
      const f16x8 bf = *(const f16x8*)&w2ht[c * 128 + k0 + qk * 8];
      dacc[t] = __builtin_amdgcn_mfma_f32_16x16x32_f16(af, bf, dacc[t], 0, 0, 0);
    }
  }
  #pragma unroll
  for (int t = 0; t < 2; ++t) {
    const int c = wv * 32 + t * 16 + rc;
    #pragma unroll
    for (int r = 0; r < 4; ++r) {
      const int mm = qk * 4 + r;
      const float x = embed[(size_t)sZ[mm] * 128 + c] + dacc[t][r];
      sA[swz(mm, c)] = (f16)x;
    }
  }
  __syncthreads();

  // MLP 128 -> 64; wave covers cols wv*16..+15
  const int c1 = wv * 16 + rc;
  const float bm = mb1[c1];
  f32x4 a2 = (f32x4){bm, bm, bm, bm};
  #pragma unroll
  for (int k0 = 0; k0 < 128; k0 += 32) {
    const f16x8 af = AFRAG(sA, k0);
    const f16x8 bf = *(const f16x8*)&mw1ht[c1 * 128 + k0 + qk * 8];
    a2 = __builtin_amdgcn_mfma_f32_16x16x32_f16(af, bf, a2, 0, 0, 0);
  }

  // MLP 64 -> 1 + block sum
  const float cm = mw2[c1];
  float v = 0.0f;
  #pragma unroll
  for (int r = 0; r < 4; ++r) v = fmaf(ssp(a2[r]), cm, v);
  #pragma unroll
  for (int o = 1; o < 64; o <<= 1) v += __shfl_xor(v, o, 64);
  if (l == 0) sRed[wv] = v;
  __syncthreads();
  if (tid == 0) {
    atomicAdd(out, 20.0f * (sRed[0] + sRed[1] + sRed[2] + sRed[3] + 16.0f * mb2[0]));
  }
#undef AFRAG
}

extern "C" void kernel_launch(void* const* d_in, const int* in_sizes, int n_in,
                              void* d_out, int out_size, void* d_ws, size_t ws_size,
                              hipStream_t stream) {
  const float* dR    = (const float*)d_in[0];
  const int*   Z     = (const int*)  d_in[1];
  const int*   nbr   = (const int*)  d_in[2];
  const float* embed = (const float*)d_in[3];
  const float* fw1   = (const float*)d_in[4];
  const float* fb1   = (const float*)d_in[5];
  const float* fw2   = (const float*)d_in[6];
  const float* fb2   = (const float*)d_in[7];
  const float* in2f  = (const float*)d_in[8];
  const float* w1    = (const float*)d_in[9];
  const float* b1    = (const float*)d_in[10];
  const float* w2    = (const float*)d_in[11];
  const float* b2    = (const float*)d_in[12];
  const float* mw1   = (const float*)d_in[13];
  const float* mb1   = (const float*)d_in[14];
  const float* mw2   = (const float*)d_in[15];
  const float* mb2   = (const float*)d_in[16];
  float* out = (float*)d_out;

  char* ws = (char*)d_ws;
  f16* tabh  = (f16*)ws;                                   // 48 KB
  f16* ytab  = (f16*)(ws + (size_t)64 * 1024);             // 25.6 KB
  f16* w1ht  = (f16*)(ws + (size_t)128 * 1024);            // 32 KB
  f16* w2ht  = (f16*)(ws + (size_t)192 * 1024);            // 32 KB
  f16* mw1ht = (f16*)(ws + (size_t)256 * 1024);            // 16 KB
  f16* agg   = (f16*)(ws + (size_t)512 * 1024);            // 12.8 MB

  prep_all_kernel<<<NTB + 64, 256, 0, stream>>>(fw1, fb1, fw2, fb2,
      w1, w2, mw1, embed, in2f, tabh, ytab, w1ht, w2ht, mw1ht, out);
  cfconv_kernel<<<ABLOCKS, 512, 0, stream>>>(dR, Z, nbr, tabh, ytab, agg);
  dense_kernel<<<N_ATOMS / 16, 256, 0, stream>>>(Z, embed, agg,
      w1ht, b1, w2ht, b2, mw1ht, mb1, mw2, mb2, out);
}

// Round 12
// 72.940 us; speedup vs baseline: 1.1750x; 1.1750x over previous
//
#include <hip/hip_runtime.h>
#include <math.h>

#define N_ATOMS  50000
#define N_NBRS   32
#define N_GAUSS  25
#define RCUT     5.0f
#define TT       192       // nearest-table nodes, spacing RCUT/191
#define TROWS    32
#define NTB      6         // 192/32 table-build blocks
#define MAXZ     100
#define NT32     1563      // ceil(50000/32) 32-atom chunks
#define ABLOCKS  512       // persistent cfconv blocks (2 per CU)
#define NDB      (N_ATOMS / 16)   // 3125 dense blocks
#define PI_F     3.14159265358979323846f

typedef unsigned int   uint_t;
typedef unsigned short ushort_t;
typedef _Float16 f16;
typedef f16   f16x2 __attribute__((ext_vector_type(2)));
typedef f16   f16x4 __attribute__((ext_vector_type(4)));
typedef f16   f16x8 __attribute__((ext_vector_type(8)));
typedef float f32x4 __attribute__((ext_vector_type(4)));

// fast shifted softplus: max(x,0) + log(0.5 + 0.5*exp(-|x|))
__device__ __forceinline__ float ssp(float x) {
  return fmaxf(x, 0.0f) + __logf(fmaf(0.5f, __expf(-fabsf(x)), 0.5f));
}
__device__ __forceinline__ f16x2 bch(uint_t u) {
  return __builtin_bit_cast(f16x2, u);
}
__device__ __forceinline__ uint_t hcb(f16x2 v) {
  return __builtin_bit_cast(uint_t, v);
}
// swizzled element offset into a [16][128] f16 LDS tile
__device__ __forceinline__ int swz(int m, int e) {
  return m * 128 + ((((e >> 3) ^ m) & 15) << 3) + (e & 7);
}

// ---- prep: blocks [0,NTB) build nearest table; blocks [NTB,NTB+64) transposes+ytab
__global__ void __launch_bounds__(256, 2)
prep_all_kernel(const float* __restrict__ fw1,
                const float* __restrict__ fb1,
                const float* __restrict__ fw2,
                const float* __restrict__ fb2,
                const float* __restrict__ w1,
                const float* __restrict__ w2,
                const float* __restrict__ mw1,
                const float* __restrict__ embed,
                const float* __restrict__ in2f,
                f16* __restrict__ tabh,
                f16* __restrict__ ytab,
                f16* __restrict__ w1ht,
                f16* __restrict__ w2ht,
                f16* __restrict__ mw1ht) {
  const int tid = threadIdx.x;
  const int bid = blockIdx.x;

  __shared__ float sW2[128 * 128];       // 64 KB
  __shared__ float sH[TROWS][128];       // 16 KB

  if (bid < NTB) {
    const int i0 = bid * TROWS;
    #pragma unroll
    for (int t = 0; t < 16; ++t) {
      const int e = tid + t * 256;
      ((float4*)sW2)[e] = ((const float4*)fw2)[e];
    }
    // phase 1: H[row][f] = ssp(gauss(r_row) . fw1[:,f] + fb1[f])
    {
      const int f  = tid & 127;
      const int rh = (tid >> 7) * (TROWS / 2);
      const float delta = RCUT / (float)(N_GAUSS - 1);
      const float coeff = -0.5f / (delta * delta);
      const float b1v = fb1[f];
      for (int j = 0; j < TROWS / 2; ++j) {
        const float r = (float)(i0 + rh + j) * (RCUT / 191.0f);
        float h = b1v;
        #pragma unroll
        for (int g = 0; g < N_GAUSS; ++g) {
          const float d = r - (float)g * delta;
          h = fmaf(__expf(coeff * d * d), fw1[g * 128 + f], h);
        }
        sH[rh + j][f] = ssp(h);
      }
    }
    __syncthreads();
    // phase 2: tab[row][c] = H[row][:] @ fw2[:,c] + fb2[c]
    {
      const int c0 = (tid & 31) * 4;
      const int rg = (tid >> 5) * 4;
      f32x4 acc[4];
      const float4 bv = *(const float4*)&fb2[c0];
      #pragma unroll
      for (int j = 0; j < 4; ++j) acc[j] = (f32x4){bv.x, bv.y, bv.z, bv.w};
      for (int k = 0; k < 128; ++k) {
        const float4 wv = *(const float4*)&sW2[k * 128 + c0];
        #pragma unroll
        for (int j = 0; j < 4; ++j) {
          const float hv = sH[rg + j][k];
          acc[j][0] = fmaf(hv, wv.x, acc[j][0]);
          acc[j][1] = fmaf(hv, wv.y, acc[j][1]);
          acc[j][2] = fmaf(hv, wv.z, acc[j][2]);
          acc[j][3] = fmaf(hv, wv.w, acc[j][3]);
        }
      }
      #pragma unroll
      for (int j = 0; j < 4; ++j) {
        const int i = i0 + rg + j;
        const float r = (float)i * (RCUT / 191.0f);
        const float fc = (r < RCUT) ? 0.5f * (__cosf(r * PI_F / RCUT) + 1.0f) : 0.0f;
        f16x4 o;
        #pragma unroll
        for (int c = 0; c < 4; ++c) o[c] = (f16)(acc[j][c] * fc);
        *(f16x4*)&tabh[i * 128 + c0] = o;
      }
    }
  } else {
    const int cc = (bid - NTB) * 2 + (tid >> 7);
    const int i  = tid & 127;
    w1ht[cc * 128 + i] = (f16)w1[i * 128 + cc];
    w2ht[cc * 128 + i] = (f16)w2[i * 128 + cc];
    if (cc < 64) mw1ht[cc * 128 + i] = (f16)mw1[i * 64 + cc];
    float* xs = &sH[0][0] + (tid >> 7) * 128;
    xs[i] = (cc < MAXZ) ? embed[cc * 128 + i] : 0.0f;
    __syncthreads();
    if (cc < MAXZ) {
      float acc = 0.0f;
      for (int j = 0; j < 128; j += 4) {
        const float4 xv = *reinterpret_cast<const float4*>(&xs[j]);
        acc = fmaf(xv.x, in2f[(j + 0) * 128 + i], acc);
        acc = fmaf(xv.y, in2f[(j + 1) * 128 + i], acc);
        acc = fmaf(xv.z, in2f[(j + 2) * 128 + i], acc);
        acc = fmaf(xv.w, in2f[(j + 3) * 128 + i], acc);
      }
      ytab[cc * 128 + i] = (f16)acc;
    }
  }
}

// ---- kernel A: cfconv only. Persistent 512-thread blocks, quarter-wave = atom,
//      lane = 8 channels, nearest table + ytab LDS-resident, 2 barriers/chunk.
__global__ void __launch_bounds__(512, 4)
cfconv_kernel(const float* __restrict__ dR,
              const int* __restrict__ Z,
              const int* __restrict__ nbr,
              const f16* __restrict__ tabh,
              const f16* __restrict__ ytab,
              f16* __restrict__ agg) {
  const int tid = threadIdx.x;
  __shared__ __align__(16) f16    sW[TT * 128];     // 48 KB
  __shared__ __align__(16) f16    sYT[MAXZ * 128];  // 25.6 KB
  __shared__ __align__(16) uint_t s_pk[1024];       // 4 KB: i0 | (z<<8)

  for (int e = tid; e < TT * 16; e += 512)   ((uint4*)sW)[e]  = ((const uint4*)tabh)[e];
  for (int e = tid; e < MAXZ * 16; e += 512) ((uint4*)sYT)[e] = ((const uint4*)ytab)[e];

  const int w  = tid >> 6;        // wave 0..7
  const int l  = tid & 63;
  const int q  = l >> 4;          // quarter = atom within wave's group
  const int cq = l & 15;          // lane -> channels 8cq..8cq+7
  const int m  = w * 4 + q;       // atom 0..31 within chunk
  const char* wb = (const char*)sW  + cq * 16;
  const char* yb = (const char*)sYT + cq * 16;

  for (int tile = blockIdx.x; tile < NT32; tile += ABLOCKS) {
    const int a0 = tile * 32;
    __syncthreads();   // previous chunk's s_pk reads done (also covers table staging)
    #pragma unroll
    for (int t0 = 0; t0 < 2; ++t0) {
      const int t = tid + t0 * 512;
      const int pidx = a0 * N_NBRS + t;
      if (pidx < N_ATOMS * N_NBRS) {
        const float r = dR[pidx];
        const int  nb = nbr[pidx];
        int i0 = (int)(r * (191.0f / RCUT) + 0.5f);
        i0 = min(i0, 191);
        s_pk[t] = (uint_t)i0 | ((uint_t)Z[nb] << 8);
      }
    }
    __syncthreads();

    const int a = a0 + m;
    if (a < N_ATOMS) {
      f16x2 acc[4];
      #pragma unroll
      for (int c = 0; c < 4; ++c) acc[c] = (f16x2)0;

      uint4 twA[4], ytA[4], twB[4], ytB[4];

#define IG(BK, g) { \
    _Pragma("unroll") \
    for (int d = 0; d < 4; ++d) { \
      const uint_t pk = s_pk[m * N_NBRS + (g) * 4 + d]; \
      tw##BK[d] = *(const uint4*)(wb + ((pk & 0xFFu) << 8)); \
      yt##BK[d] = *(const uint4*)(yb + ((pk >> 8) << 8)); \
    } }

#define CG(BK) { \
    _Pragma("unroll") \
    for (int d = 0; d < 4; ++d) { \
      acc[0] += bch(tw##BK[d].x) * bch(yt##BK[d].x); \
      acc[1] += bch(tw##BK[d].y) * bch(yt##BK[d].y); \
      acc[2] += bch(tw##BK[d].z) * bch(yt##BK[d].z); \
      acc[3] += bch(tw##BK[d].w) * bch(yt##BK[d].w); \
    } }

      IG(A, 0) IG(B, 1)
      CG(A) IG(A, 2)
      CG(B) IG(B, 3)
      CG(A) IG(A, 4)
      CG(B) IG(B, 5)
      CG(A) IG(A, 6)
      CG(B) IG(B, 7)
      CG(A)
      CG(B)
#undef IG
#undef CG

      uint4 o;
      o.x = hcb(acc[0]); o.y = hcb(acc[1]); o.z = hcb(acc[2]); o.w = hcb(acc[3]);
      *(uint4*)&agg[(size_t)a * 128 + cq * 8] = o;
    }
  }
}

// ---- kernel B: dense pipeline per 16-atom block; writes PARTIAL sums (no atomic)
__global__ void __launch_bounds__(256, 4)
dense_kernel(const int* __restrict__ Z,
             const float* __restrict__ embed,
             const f16* __restrict__ agg,
             const f16* __restrict__ w1ht, const float* __restrict__ b1,
             const f16* __restrict__ w2ht, const float* __restrict__ b2,
             const f16* __restrict__ mw1ht, const float* __restrict__ mb1,
             const float* __restrict__ mw2,
             float* __restrict__ partial) {
  const int tid = threadIdx.x;
  const int wv  = tid >> 6;
  const int l   = tid & 63;
  const int a0  = blockIdx.x * 16;
  __shared__ __align__(16) f16 sA[16 * 128];
  __shared__ __align__(16) f16 sB[16 * 128];
  __shared__ int   sZ[16];
  __shared__ float sRed[4];

  // stage agg tile -> sA (swizzled write, coalesced read)
  {
    const int mm = tid >> 4, cc = tid & 15;
    const uint4 v = ((const uint4*)agg)[a0 * 16 + tid];
    *(uint4*)&sA[mm * 128 + (((cc ^ mm) & 15) << 3)] = v;
  }
  if (tid < 16) sZ[tid] = Z[a0 + tid];
  __syncthreads();

  const int rc = l & 15;
  const int qk = l >> 4;
#define AFRAG(SRC, k0) (*(const f16x8*)&SRC[rc * 128 + (((((k0) >> 3) + qk) ^ rc) & 15) * 8])

  // f2out layer 1: wave covers cols wv*32..+31
  f32x4 dacc[2];
  #pragma unroll
  for (int t = 0; t < 2; ++t) {
    const float b = b1[wv * 32 + t * 16 + rc];
    dacc[t] = (f32x4){b, b, b, b};
  }
  #pragma unroll
  for (int k0 = 0; k0 < 128; k0 += 32) {
    const f16x8 af = AFRAG(sA, k0);
    #pragma unroll
    for (int t = 0; t < 2; ++t) {
      const int c = wv * 32 + t * 16 + rc;
      const f16x8 bf = *(const f16x8*)&w1ht[c * 128 + k0 + qk * 8];
      dacc[t] = __builtin_amdgcn_mfma_f32_16x16x32_f16(af, bf, dacc[t], 0, 0, 0);
    }
  }
  #pragma unroll
  for (int t = 0; t < 2; ++t) {
    const int c = wv * 32 + t * 16 + rc;
    #pragma unroll
    for (int r = 0; r < 4; ++r) {
      sB[swz(qk * 4 + r, c)] = (f16)ssp(dacc[t][r]);
    }
  }
  __syncthreads();

  // f2out layer 2 + residual -> sA
  #pragma unroll
  for (int t = 0; t < 2; ++t) {
    const float b = b2[wv * 32 + t * 16 + rc];
    dacc[t] = (f32x4){b, b, b, b};
  }
  #pragma unroll
  for (int k0 = 0; k0 < 128; k0 += 32) {
    const f16x8 af = AFRAG(sB, k0);
    #pragma unroll
    for (int t = 0; t < 2; ++t) {
      const int c = wv * 32 + t * 16 + rc;
      const f16x8 bf = *(const f16x8*)&w2ht[c * 128 + k0 + qk * 8];
      dacc[t] = __builtin_amdgcn_mfma_f32_16x16x32_f16(af, bf, dacc[t], 0, 0, 0);
    }
  }
  #pragma unroll
  for (int t = 0; t < 2; ++t) {
    const int c = wv * 32 + t * 16 + rc;
    #pragma unroll
    for (int r = 0; r < 4; ++r) {
      const int mm = qk * 4 + r;
      const float x = embed[(size_t)sZ[mm] * 128 + c] + dacc[t][r];
      sA[swz(mm, c)] = (f16)x;
    }
  }
  __syncthreads();

  // MLP 128 -> 64; wave covers cols wv*16..+15
  const int c1 = wv * 16 + rc;
  const float bm = mb1[c1];
  f32x4 a2 = (f32x4){bm, bm, bm, bm};
  #pragma unroll
  for (int k0 = 0; k0 < 128; k0 += 32) {
    const f16x8 af = AFRAG(sA, k0);
    const f16x8 bf = *(const f16x8*)&mw1ht[c1 * 128 + k0 + qk * 8];
    a2 = __builtin_amdgcn_mfma_f32_16x16x32_f16(af, bf, a2, 0, 0, 0);
  }

  // MLP 64 -> 1 + block sum -> partial store (no atomic)
  const float cm = mw2[c1];
  float v = 0.0f;
  #pragma unroll
  for (int r = 0; r < 4; ++r) v = fmaf(ssp(a2[r]), cm, v);
  #pragma unroll
  for (int o = 1; o < 64; o <<= 1) v += __shfl_xor(v, o, 64);
  if (l == 0) sRed[wv] = v;
  __syncthreads();
  if (tid == 0) {
    partial[blockIdx.x] = sRed[0] + sRed[1] + sRed[2] + sRed[3];
  }
#undef AFRAG
}

// ---- final reduce: one block sums the 3125 partials, applies bias + scale ----
__global__ void __launch_bounds__(256, 1)
reduce_kernel(const float* __restrict__ partial,
              const float* __restrict__ mb2,
              float* __restrict__ out) {
  const int tid = threadIdx.x;
  float s = 0.0f;
  for (int i = tid; i < NDB; i += 256) s += partial[i];
  __shared__ float sr[4];
  #pragma unroll
  for (int o = 1; o < 64; o <<= 1) s += __shfl_xor(s, o, 64);
  if ((tid & 63) == 0) sr[tid >> 6] = s;
  __syncthreads();
  if (tid == 0) {
    out[0] = 20.0f * (sr[0] + sr[1] + sr[2] + sr[3] + (float)N_ATOMS * mb2[0]);
  }
}

extern "C" void kernel_launch(void* const* d_in, const int* in_sizes, int n_in,
                              void* d_out, int out_size, void* d_ws, size_t ws_size,
                              hipStream_t stream) {
  const float* dR    = (const float*)d_in[0];
  const int*   Z     = (const int*)  d_in[1];
  const int*   nbr   = (const int*)  d_in[2];
  const float* embed = (const float*)d_in[3];
  const float* fw1   = (const float*)d_in[4];
  const float* fb1   = (const float*)d_in[5];
  const float* fw2   = (const float*)d_in[6];
  const float* fb2   = (const float*)d_in[7];
  const float* in2f  = (const float*)d_in[8];
  const float* w1    = (const float*)d_in[9];
  const float* b1    = (const float*)d_in[10];
  const float* w2    = (const float*)d_in[11];
  const float* b2    = (const float*)d_in[12];
  const float* mw1   = (const float*)d_in[13];
  const float* mb1   = (const float*)d_in[14];
  const float* mw2   = (const float*)d_in[15];
  const float* mb2   = (const float*)d_in[16];
  float* out = (float*)d_out;

  char* ws = (char*)d_ws;
  f16*   tabh    = (f16*)ws;                               // 48 KB
  f16*   ytab    = (f16*)(ws + (size_t)64 * 1024);         // 25.6 KB
  f16*   w1ht    = (f16*)(ws + (size_t)128 * 1024);        // 32 KB
  f16*   w2ht    = (f16*)(ws + (size_t)192 * 1024);        // 32 KB
  f16*   mw1ht   = (f16*)(ws + (size_t)256 * 1024);        // 16 KB
  float* partial = (float*)(ws + (size_t)384 * 1024);      // 12.5 KB
  f16*   agg     = (f16*)(ws + (size_t)512 * 1024);        // 12.8 MB

  prep_all_kernel<<<NTB + 64, 256, 0, stream>>>(fw1, fb1, fw2, fb2,
      w1, w2, mw1, embed, in2f, tabh, ytab, w1ht, w2ht, mw1ht);
  cfconv_kernel<<<ABLOCKS, 512, 0, stream>>>(dR, Z, nbr, tabh, ytab, agg);
  dense_kernel<<<NDB, 256, 0, stream>>>(Z, embed, agg,
      w1ht, b1, w2ht, b2, mw1ht, mb1, mw2, partial);
  reduce_kernel<<<1, 256, 0, stream>>>(partial, mb2, out);
}

// Round 13
// 61.115 us; speedup vs baseline: 1.4023x; 1.1935x over previous
//
#include <hip/hip_runtime.h>
#include <math.h>

#define N_ATOMS  50000
#define N_NBRS   32
#define N_GAUSS  25
#define RCUT     5.0f
#define TT       192       // nearest-table nodes, spacing RCUT/191
#define TROWS    32
#define NTB      6         // 192/32 table-build blocks
#define MAXZ     100
#define NT32     1563      // ceil(50000/32) 32-atom chunks
#define ABLOCKS  512       // persistent cfconv blocks (2 per CU)
#define NTILES   (N_ATOMS / 16)   // 3125 dense tiles
#define DBLOCKS  1024      // persistent dense blocks
#define PI_F     3.14159265358979323846f

typedef unsigned int   uint_t;
typedef unsigned short ushort_t;
typedef _Float16 f16;
typedef f16   f16x2 __attribute__((ext_vector_type(2)));
typedef f16   f16x4 __attribute__((ext_vector_type(4)));
typedef f16   f16x8 __attribute__((ext_vector_type(8)));
typedef float f32x4 __attribute__((ext_vector_type(4)));

// fast shifted softplus: max(x,0) + log(0.5 + 0.5*exp(-|x|))
__device__ __forceinline__ float ssp(float x) {
  return fmaxf(x, 0.0f) + __logf(fmaf(0.5f, __expf(-fabsf(x)), 0.5f));
}
__device__ __forceinline__ f16x2 bch(uint_t u) {
  return __builtin_bit_cast(f16x2, u);
}
__device__ __forceinline__ uint_t hcb(f16x2 v) {
  return __builtin_bit_cast(uint_t, v);
}
// swizzled element offset into a [16][128] f16 LDS tile
__device__ __forceinline__ int swz(int m, int e) {
  return m * 128 + ((((e >> 3) ^ m) & 15) << 3) + (e & 7);
}

// ---- prep: blocks [0,NTB) build nearest table; blocks [NTB,NTB+64) transposes+ytab
__global__ void __launch_bounds__(256, 2)
prep_all_kernel(const float* __restrict__ fw1,
                const float* __restrict__ fb1,
                const float* __restrict__ fw2,
                const float* __restrict__ fb2,
                const float* __restrict__ w1,
                const float* __restrict__ w2,
                const float* __restrict__ mw1,
                const float* __restrict__ embed,
                const float* __restrict__ in2f,
                f16* __restrict__ tabh,
                f16* __restrict__ ytab,
                f16* __restrict__ w1ht,
                f16* __restrict__ w2ht,
                f16* __restrict__ mw1ht) {
  const int tid = threadIdx.x;
  const int bid = blockIdx.x;

  __shared__ float sW2[128 * 128];       // 64 KB
  __shared__ float sH[TROWS][128];       // 16 KB

  if (bid < NTB) {
    const int i0 = bid * TROWS;
    #pragma unroll
    for (int t = 0; t < 16; ++t) {
      const int e = tid + t * 256;
      ((float4*)sW2)[e] = ((const float4*)fw2)[e];
    }
    // phase 1: H[row][f] = ssp(gauss(r_row) . fw1[:,f] + fb1[f])
    {
      const int f  = tid & 127;
      const int rh = (tid >> 7) * (TROWS / 2);
      const float delta = RCUT / (float)(N_GAUSS - 1);
      const float coeff = -0.5f / (delta * delta);
      const float b1v = fb1[f];
      for (int j = 0; j < TROWS / 2; ++j) {
        const float r = (float)(i0 + rh + j) * (RCUT / 191.0f);
        float h = b1v;
        #pragma unroll
        for (int g = 0; g < N_GAUSS; ++g) {
          const float d = r - (float)g * delta;
          h = fmaf(__expf(coeff * d * d), fw1[g * 128 + f], h);
        }
        sH[rh + j][f] = ssp(h);
      }
    }
    __syncthreads();
    // phase 2: tab[row][c] = H[row][:] @ fw2[:,c] + fb2[c]
    {
      const int c0 = (tid & 31) * 4;
      const int rg = (tid >> 5) * 4;
      f32x4 acc[4];
      const float4 bv = *(const float4*)&fb2[c0];
      #pragma unroll
      for (int j = 0; j < 4; ++j) acc[j] = (f32x4){bv.x, bv.y, bv.z, bv.w};
      for (int k = 0; k < 128; ++k) {
        const float4 wv = *(const float4*)&sW2[k * 128 + c0];
        #pragma unroll
        for (int j = 0; j < 4; ++j) {
          const float hv = sH[rg + j][k];
          acc[j][0] = fmaf(hv, wv.x, acc[j][0]);
          acc[j][1] = fmaf(hv, wv.y, acc[j][1]);
          acc[j][2] = fmaf(hv, wv.z, acc[j][2]);
          acc[j][3] = fmaf(hv, wv.w, acc[j][3]);
        }
      }
      #pragma unroll
      for (int j = 0; j < 4; ++j) {
        const int i = i0 + rg + j;
        const float r = (float)i * (RCUT / 191.0f);
        const float fc = (r < RCUT) ? 0.5f * (__cosf(r * PI_F / RCUT) + 1.0f) : 0.0f;
        f16x4 o;
        #pragma unroll
        for (int c = 0; c < 4; ++c) o[c] = (f16)(acc[j][c] * fc);
        *(f16x4*)&tabh[i * 128 + c0] = o;
      }
    }
  } else {
    const int cc = (bid - NTB) * 2 + (tid >> 7);
    const int i  = tid & 127;
    w1ht[cc * 128 + i] = (f16)w1[i * 128 + cc];
    w2ht[cc * 128 + i] = (f16)w2[i * 128 + cc];
    if (cc < 64) mw1ht[cc * 128 + i] = (f16)mw1[i * 64 + cc];
    float* xs = &sH[0][0] + (tid >> 7) * 128;
    xs[i] = (cc < MAXZ) ? embed[cc * 128 + i] : 0.0f;
    __syncthreads();
    if (cc < MAXZ) {
      float acc = 0.0f;
      for (int j = 0; j < 128; j += 4) {
        const float4 xv = *reinterpret_cast<const float4*>(&xs[j]);
        acc = fmaf(xv.x, in2f[(j + 0) * 128 + i], acc);
        acc = fmaf(xv.y, in2f[(j + 1) * 128 + i], acc);
        acc = fmaf(xv.z, in2f[(j + 2) * 128 + i], acc);
        acc = fmaf(xv.w, in2f[(j + 3) * 128 + i], acc);
      }
      ytab[cc * 128 + i] = (f16)acc;
    }
  }
}

// ---- kernel A: cfconv only (unchanged from R12) ----
__global__ void __launch_bounds__(512, 4)
cfconv_kernel(const float* __restrict__ dR,
              const int* __restrict__ Z,
              const int* __restrict__ nbr,
              const f16* __restrict__ tabh,
              const f16* __restrict__ ytab,
              f16* __restrict__ agg) {
  const int tid = threadIdx.x;
  __shared__ __align__(16) f16    sW[TT * 128];     // 48 KB
  __shared__ __align__(16) f16    sYT[MAXZ * 128];  // 25.6 KB
  __shared__ __align__(16) uint_t s_pk[1024];       // 4 KB: i0 | (z<<8)

  for (int e = tid; e < TT * 16; e += 512)   ((uint4*)sW)[e]  = ((const uint4*)tabh)[e];
  for (int e = tid; e < MAXZ * 16; e += 512) ((uint4*)sYT)[e] = ((const uint4*)ytab)[e];

  const int w  = tid >> 6;
  const int l  = tid & 63;
  const int q  = l >> 4;
  const int cq = l & 15;
  const int m  = w * 4 + q;
  const char* wb = (const char*)sW  + cq * 16;
  const char* yb = (const char*)sYT + cq * 16;

  for (int tile = blockIdx.x; tile < NT32; tile += ABLOCKS) {
    const int a0 = tile * 32;
    __syncthreads();
    #pragma unroll
    for (int t0 = 0; t0 < 2; ++t0) {
      const int t = tid + t0 * 512;
      const int pidx = a0 * N_NBRS + t;
      if (pidx < N_ATOMS * N_NBRS) {
        const float r = dR[pidx];
        const int  nb = nbr[pidx];
        int i0 = (int)(r * (191.0f / RCUT) + 0.5f);
        i0 = min(i0, 191);
        s_pk[t] = (uint_t)i0 | ((uint_t)Z[nb] << 8);
      }
    }
    __syncthreads();

    const int a = a0 + m;
    if (a < N_ATOMS) {
      f16x2 acc[4];
      #pragma unroll
      for (int c = 0; c < 4; ++c) acc[c] = (f16x2)0;

      uint4 twA[4], ytA[4], twB[4], ytB[4];

#define IG(BK, g) { \
    _Pragma("unroll") \
    for (int d = 0; d < 4; ++d) { \
      const uint_t pk = s_pk[m * N_NBRS + (g) * 4 + d]; \
      tw##BK[d] = *(const uint4*)(wb + ((pk & 0xFFu) << 8)); \
      yt##BK[d] = *(const uint4*)(yb + ((pk >> 8) << 8)); \
    } }

#define CG(BK) { \
    _Pragma("unroll") \
    for (int d = 0; d < 4; ++d) { \
      acc[0] += bch(tw##BK[d].x) * bch(yt##BK[d].x); \
      acc[1] += bch(tw##BK[d].y) * bch(yt##BK[d].y); \
      acc[2] += bch(tw##BK[d].z) * bch(yt##BK[d].z); \
      acc[3] += bch(tw##BK[d].w) * bch(yt##BK[d].w); \
    } }

      IG(A, 0) IG(B, 1)
      CG(A) IG(A, 2)
      CG(B) IG(B, 3)
      CG(A) IG(A, 4)
      CG(B) IG(B, 5)
      CG(A) IG(A, 6)
      CG(B) IG(B, 7)
      CG(A)
      CG(B)
#undef IG
#undef CG

      uint4 o;
      o.x = hcb(acc[0]); o.y = hcb(acc[1]); o.z = hcb(acc[2]); o.w = hcb(acc[3]);
      *(uint4*)&agg[(size_t)a * 128 + cq * 8] = o;
    }
  }
}

// ---- kernel B: PERSISTENT dense pipeline, weights in registers, no atomics ----
__global__ void __launch_bounds__(256, 3)
dense_kernel(const int* __restrict__ Z,
             const float* __restrict__ embed,
             const f16* __restrict__ agg,
             const f16* __restrict__ w1ht, const float* __restrict__ b1,
             const f16* __restrict__ w2ht, const float* __restrict__ b2,
             const f16* __restrict__ mw1ht, const float* __restrict__ mb1,
             const float* __restrict__ mw2,
             float* __restrict__ partial) {
  const int tid = threadIdx.x;
  const int wv  = tid >> 6;
  const int l   = tid & 63;
  const int rc  = l & 15;
  const int qk  = l >> 4;
  __shared__ __align__(16) f16 sA[16 * 128];
  __shared__ __align__(16) f16 sB[16 * 128];
  __shared__ int   sZ[16];
  __shared__ float sRed[4];

  // ---- load all weight fragments + biases ONCE (loop-invariant) ----
  f16x8 bw1[2][4], bw2[2][4], bwm[4];
  float bb1[2], bb2[2];
  #pragma unroll
  for (int t = 0; t < 2; ++t) {
    const int c = wv * 32 + t * 16 + rc;
    bb1[t] = b1[c];
    bb2[t] = b2[c];
    #pragma unroll
    for (int k0i = 0; k0i < 4; ++k0i) {
      bw1[t][k0i] = *(const f16x8*)&w1ht[c * 128 + k0i * 32 + qk * 8];
      bw2[t][k0i] = *(const f16x8*)&w2ht[c * 128 + k0i * 32 + qk * 8];
    }
  }
  const int c1 = wv * 16 + rc;
  #pragma unroll
  for (int k0i = 0; k0i < 4; ++k0i) {
    bwm[k0i] = *(const f16x8*)&mw1ht[c1 * 128 + k0i * 32 + qk * 8];
  }
  const float bm = mb1[c1];
  const float cm = mw2[c1];

  float vsum = 0.0f;   // per-thread running sum across tiles

#define AFRAG(SRC, k0) (*(const f16x8*)&SRC[rc * 128 + (((((k0) >> 3) + qk) ^ rc) & 15) * 8])

  for (int tile = blockIdx.x; tile < NTILES; tile += DBLOCKS) {
    const int a0 = tile * 16;
    __syncthreads();   // previous tile's sA reads (MLP) complete

    // stage agg tile -> sA (swizzled write, coalesced read)
    {
      const int mm = tid >> 4, cc = tid & 15;
      const uint4 v = ((const uint4*)agg)[a0 * 16 + tid];
      *(uint4*)&sA[mm * 128 + (((cc ^ mm) & 15) << 3)] = v;
    }
    if (tid < 16) sZ[tid] = Z[a0 + tid];
    __syncthreads();

    // f2out layer 1
    f32x4 dacc[2];
    #pragma unroll
    for (int t = 0; t < 2; ++t) dacc[t] = (f32x4){bb1[t], bb1[t], bb1[t], bb1[t]};
    #pragma unroll
    for (int k0i = 0; k0i < 4; ++k0i) {
      const f16x8 af = AFRAG(sA, k0i * 32);
      #pragma unroll
      for (int t = 0; t < 2; ++t)
        dacc[t] = __builtin_amdgcn_mfma_f32_16x16x32_f16(af, bw1[t][k0i], dacc[t], 0, 0, 0);
    }
    #pragma unroll
    for (int t = 0; t < 2; ++t) {
      const int c = wv * 32 + t * 16 + rc;
      #pragma unroll
      for (int r = 0; r < 4; ++r) sB[swz(qk * 4 + r, c)] = (f16)ssp(dacc[t][r]);
    }
    __syncthreads();

    // f2out layer 2 + residual -> sA
    #pragma unroll
    for (int t = 0; t < 2; ++t) dacc[t] = (f32x4){bb2[t], bb2[t], bb2[t], bb2[t]};
    #pragma unroll
    for (int k0i = 0; k0i < 4; ++k0i) {
      const f16x8 af = AFRAG(sB, k0i * 32);
      #pragma unroll
      for (int t = 0; t < 2; ++t)
        dacc[t] = __builtin_amdgcn_mfma_f32_16x16x32_f16(af, bw2[t][k0i], dacc[t], 0, 0, 0);
    }
    #pragma unroll
    for (int t = 0; t < 2; ++t) {
      const int c = wv * 32 + t * 16 + rc;
      #pragma unroll
      for (int r = 0; r < 4; ++r) {
        const int mm = qk * 4 + r;
        const float x = embed[(size_t)sZ[mm] * 128 + c] + dacc[t][r];
        sA[swz(mm, c)] = (f16)x;
      }
    }
    __syncthreads();

    // MLP 128 -> 64 -> 1, accumulate per-thread
    f32x4 a2 = (f32x4){bm, bm, bm, bm};
    #pragma unroll
    for (int k0i = 0; k0i < 4; ++k0i)
      a2 = __builtin_amdgcn_mfma_f32_16x16x32_f16(AFRAG(sA, k0i * 32), bwm[k0i], a2, 0, 0, 0);
    #pragma unroll
    for (int r = 0; r < 4; ++r) vsum = fmaf(ssp(a2[r]), cm, vsum);
  }
#undef AFRAG

  // block-level reduce -> partial store
  #pragma unroll
  for (int o = 1; o < 64; o <<= 1) vsum += __shfl_xor(vsum, o, 64);
  if (l == 0) sRed[wv] = vsum;
  __syncthreads();
  if (tid == 0) {
    partial[blockIdx.x] = sRed[0] + sRed[1] + sRed[2] + sRed[3];
  }
}

// ---- final reduce: one block sums the partials, applies bias + scale ----
__global__ void __launch_bounds__(256, 1)
reduce_kernel(const float* __restrict__ partial,
              const float* __restrict__ mb2,
              float* __restrict__ out) {
  const int tid = threadIdx.x;
  float s = 0.0f;
  for (int i = tid; i < DBLOCKS; i += 256) s += partial[i];
  __shared__ float sr[4];
  #pragma unroll
  for (int o = 1; o < 64; o <<= 1) s += __shfl_xor(s, o, 64);
  if ((tid & 63) == 0) sr[tid >> 6] = s;
  __syncthreads();
  if (tid == 0) {
    out[0] = 20.0f * (sr[0] + sr[1] + sr[2] + sr[3] + (float)N_ATOMS * mb2[0]);
  }
}

extern "C" void kernel_launch(void* const* d_in, const int* in_sizes, int n_in,
                              void* d_out, int out_size, void* d_ws, size_t ws_size,
                              hipStream_t stream) {
  const float* dR    = (const float*)d_in[0];
  const int*   Z     = (const int*)  d_in[1];
  const int*   nbr   = (const int*)  d_in[2];
  const float* embed = (const float*)d_in[3];
  const float* fw1   = (const float*)d_in[4];
  const float* fb1   = (const float*)d_in[5];
  const float* fw2   = (const float*)d_in[6];
  const float* fb2   = (const float*)d_in[7];
  const float* in2f  = (const float*)d_in[8];
  const float* w1    = (const float*)d_in[9];
  const float* b1    = (const float*)d_in[10];
  const float* w2    = (const float*)d_in[11];
  const float* b2    = (const float*)d_in[12];
  const float* mw1   = (const float*)d_in[13];
  const float* mb1   = (const float*)d_in[14];
  const float* mw2   = (const float*)d_in[15];
  const float* mb2   = (const float*)d_in[16];
  float* out = (float*)d_out;

  char* ws = (char*)d_ws;
  f16*   tabh    = (f16*)ws;                               // 48 KB
  f16*   ytab    = (f16*)(ws + (size_t)64 * 1024);         // 25.6 KB
  f16*   w1ht    = (f16*)(ws + (size_t)128 * 1024);        // 32 KB
  f16*   w2ht    = (f16*)(ws + (size_t)192 * 1024);        // 32 KB
  f16*   mw1ht   = (f16*)(ws + (size_t)256 * 1024);        // 16 KB
  float* partial = (float*)(ws + (size_t)384 * 1024);      // 4 KB
  f16*   agg     = (f16*)(ws + (size_t)512 * 1024);        // 12.8 MB

  prep_all_kernel<<<NTB + 64, 256, 0, stream>>>(fw1, fb1, fw2, fb2,
      w1, w2, mw1, embed, in2f, tabh, ytab, w1ht, w2ht, mw1ht);
  cfconv_kernel<<<ABLOCKS, 512, 0, stream>>>(dR, Z, nbr, tabh, ytab, agg);
  dense_kernel<<<DBLOCKS, 256, 0, stream>>>(Z, embed, agg,
      w1ht, b1, w2ht, b2, mw1ht, mb1, mw2, partial);
  reduce_kernel<<<1, 256, 0, stream>>>(partial, mb2, out);
}

// Round 14
// 55.639 us; speedup vs baseline: 1.5403x; 1.0984x over previous
//
#include <hip/hip_runtime.h>
#include <math.h>

#define N_ATOMS  50000
#define N_NBRS   32
#define N_GAUSS  25
#define RCUT     5.0f
#define TT       192       // nearest-table nodes, spacing RCUT/191
#define TROWS    32
#define NTB      6         // 192/32 table-build blocks
#define MAXZ     100
#define NT32     1563      // ceil(50000/32) 32-atom chunks
#define PBLOCKS  256       // persistent fused blocks (1 per CU)
#define PI_F     3.14159265358979323846f

typedef unsigned int   uint_t;
typedef unsigned short ushort_t;
typedef _Float16 f16;
typedef f16   f16x2 __attribute__((ext_vector_type(2)));
typedef f16   f16x4 __attribute__((ext_vector_type(4)));
typedef f16   f16x8 __attribute__((ext_vector_type(8)));
typedef float f32x4 __attribute__((ext_vector_type(4)));

// fast shifted softplus: max(x,0) + log(0.5 + 0.5*exp(-|x|))
__device__ __forceinline__ float ssp(float x) {
  return fmaxf(x, 0.0f) + __logf(fmaf(0.5f, __expf(-fabsf(x)), 0.5f));
}
__device__ __forceinline__ f16x2 bch(uint_t u) {
  return __builtin_bit_cast(f16x2, u);
}
__device__ __forceinline__ uint_t hcb(f16x2 v) {
  return __builtin_bit_cast(uint_t, v);
}
// swizzled element offset into a [16][128] f16 LDS tile
__device__ __forceinline__ int swz(int m, int e) {
  return m * 128 + ((((e >> 3) ^ m) & 15) << 3) + (e & 7);
}

// ---- prep: blocks [0,NTB) build nearest table; blocks [NTB,NTB+64) transposes+ytab
__global__ void __launch_bounds__(256, 2)
prep_all_kernel(const float* __restrict__ fw1,
                const float* __restrict__ fb1,
                const float* __restrict__ fw2,
                const float* __restrict__ fb2,
                const float* __restrict__ w1,
                const float* __restrict__ w2,
                const float* __restrict__ mw1,
                const float* __restrict__ embed,
                const float* __restrict__ in2f,
                f16* __restrict__ tabh,
                f16* __restrict__ ytab,
                f16* __restrict__ w1ht,
                f16* __restrict__ w2ht,
                f16* __restrict__ mw1ht) {
  const int tid = threadIdx.x;
  const int bid = blockIdx.x;

  __shared__ float sW2[128 * 128];       // 64 KB
  __shared__ float sH[TROWS][128];       // 16 KB

  if (bid < NTB) {
    const int i0 = bid * TROWS;
    #pragma unroll
    for (int t = 0; t < 16; ++t) {
      const int e = tid + t * 256;
      ((float4*)sW2)[e] = ((const float4*)fw2)[e];
    }
    // phase 1: H[row][f] = ssp(gauss(r_row) . fw1[:,f] + fb1[f])
    {
      const int f  = tid & 127;
      const int rh = (tid >> 7) * (TROWS / 2);
      const float delta = RCUT / (float)(N_GAUSS - 1);
      const float coeff = -0.5f / (delta * delta);
      const float b1v = fb1[f];
      for (int j = 0; j < TROWS / 2; ++j) {
        const float r = (float)(i0 + rh + j) * (RCUT / 191.0f);
        float h = b1v;
        #pragma unroll
        for (int g = 0; g < N_GAUSS; ++g) {
          const float d = r - (float)g * delta;
          h = fmaf(__expf(coeff * d * d), fw1[g * 128 + f], h);
        }
        sH[rh + j][f] = ssp(h);
      }
    }
    __syncthreads();
    // phase 2: tab[row][c] = H[row][:] @ fw2[:,c] + fb2[c]
    {
      const int c0 = (tid & 31) * 4;
      const int rg = (tid >> 5) * 4;
      f32x4 acc[4];
      const float4 bv = *(const float4*)&fb2[c0];
      #pragma unroll
      for (int j = 0; j < 4; ++j) acc[j] = (f32x4){bv.x, bv.y, bv.z, bv.w};
      for (int k = 0; k < 128; ++k) {
        const float4 wv = *(const float4*)&sW2[k * 128 + c0];
        #pragma unroll
        for (int j = 0; j < 4; ++j) {
          const float hv = sH[rg + j][k];
          acc[j][0] = fmaf(hv, wv.x, acc[j][0]);
          acc[j][1] = fmaf(hv, wv.y, acc[j][1]);
          acc[j][2] = fmaf(hv, wv.z, acc[j][2]);
          acc[j][3] = fmaf(hv, wv.w, acc[j][3]);
        }
      }
      #pragma unroll
      for (int j = 0; j < 4; ++j) {
        const int i = i0 + rg + j;
        const float r = (float)i * (RCUT / 191.0f);
        const float fc = (r < RCUT) ? 0.5f * (__cosf(r * PI_F / RCUT) + 1.0f) : 0.0f;
        f16x4 o;
        #pragma unroll
        for (int c = 0; c < 4; ++c) o[c] = (f16)(acc[j][c] * fc);
        *(f16x4*)&tabh[i * 128 + c0] = o;
      }
    }
  } else {
    const int cc = (bid - NTB) * 2 + (tid >> 7);
    const int i  = tid & 127;
    w1ht[cc * 128 + i] = (f16)w1[i * 128 + cc];
    w2ht[cc * 128 + i] = (f16)w2[i * 128 + cc];
    if (cc < 64) mw1ht[cc * 128 + i] = (f16)mw1[i * 64 + cc];
    float* xs = &sH[0][0] + (tid >> 7) * 128;
    xs[i] = (cc < MAXZ) ? embed[cc * 128 + i] : 0.0f;
    __syncthreads();
    if (cc < MAXZ) {
      float acc = 0.0f;
      for (int j = 0; j < 128; j += 4) {
        const float4 xv = *reinterpret_cast<const float4*>(&xs[j]);
        acc = fmaf(xv.x, in2f[(j + 0) * 128 + i], acc);
        acc = fmaf(xv.y, in2f[(j + 1) * 128 + i], acc);
        acc = fmaf(xv.z, in2f[(j + 2) * 128 + i], acc);
        acc = fmaf(xv.w, in2f[(j + 3) * 128 + i], acc);
      }
      ytab[cc * 128 + i] = (f16)acc;
    }
  }
}

// ---- fused kernel: cfconv + dense + MLP, persistent, no global agg, no atomics ----
__global__ void __launch_bounds__(512, 2)
fused_kernel(const float* __restrict__ dR,
             const int* __restrict__ Z,
             const int* __restrict__ nbr,
             const float* __restrict__ embed,
             const f16* __restrict__ tabh,
             const f16* __restrict__ ytab,
             const f16* __restrict__ w1ht, const float* __restrict__ b1,
             const f16* __restrict__ w2ht, const float* __restrict__ b2,
             const f16* __restrict__ mw1ht, const float* __restrict__ mb1,
             const float* __restrict__ mw2,
             float* __restrict__ partial) {
  const int tid = threadIdx.x;
  const int w   = tid >> 6;         // wave 0..7
  const int l   = tid & 63;
  const int q   = l >> 4;           // quarter 0..3 (cfconv atom-in-wave; dense k-sub)
  const int cq  = l & 15;           // cfconv channel-block / dense row-col lane
  __shared__ __align__(16) f16    sW[TT * 128];     // 48 KB nearest table
  __shared__ __align__(16) f16    sYT[MAXZ * 128];  // 25.6 KB y rows
  __shared__ __align__(16) uint_t s_pk[1024];       // 4 KB pair codes
  __shared__ __align__(16) f16    sA[2][16 * 128];  // 8 KB (two 16-atom tiles)
  __shared__ __align__(16) f16    sB[2][16 * 128];  // 8 KB
  __shared__ int   sZ[32];
  __shared__ float sRed[8];

  // -- stage tables once --
  for (int e = tid; e < TT * 16; e += 512)   ((uint4*)sW)[e]  = ((const uint4*)tabh)[e];
  for (int e = tid; e < MAXZ * 16; e += 512) ((uint4*)sYT)[e] = ((const uint4*)ytab)[e];

  // -- dense weight fragments, loaded once (group g = w>>2, wvg = w&3) --
  const int g   = w >> 2;
  const int wvg = w & 3;
  const int rc  = cq;               // A-row / C-col lane
  const int qk  = q;                // k-quarter
  f16x8 bw1[2][4], bw2[2][4], bwm[4];
  float bb1[2], bb2[2];
  #pragma unroll
  for (int t = 0; t < 2; ++t) {
    const int c = wvg * 32 + t * 16 + rc;
    bb1[t] = b1[c];
    bb2[t] = b2[c];
    #pragma unroll
    for (int k0i = 0; k0i < 4; ++k0i) {
      bw1[t][k0i] = *(const f16x8*)&w1ht[c * 128 + k0i * 32 + qk * 8];
      bw2[t][k0i] = *(const f16x8*)&w2ht[c * 128 + k0i * 32 + qk * 8];
    }
  }
  const int c1 = wvg * 16 + rc;
  #pragma unroll
  for (int k0i = 0; k0i < 4; ++k0i) {
    bwm[k0i] = *(const f16x8*)&mw1ht[c1 * 128 + k0i * 32 + qk * 8];
  }
  const float bm = mb1[c1];
  const float cm = mw2[c1];

  const int m = w * 4 + q;          // cfconv atom within 32-chunk
  const char* wb = (const char*)sW  + cq * 16;
  const char* yb = (const char*)sYT + cq * 16;

  float vsum = 0.0f;
  __syncthreads();   // tables staged

#define AFRAG(SRC, k0) (*(const f16x8*)&SRC[rc * 128 + (((((k0) >> 3) + qk) ^ rc) & 15) * 8])

  for (int chunk = blockIdx.x; chunk < NT32; chunk += PBLOCKS) {
    const int a0 = chunk * 32;
    __syncthreads();   // previous chunk's MLP sA reads complete

    // -- stage pair codes (coalesced) --
    #pragma unroll
    for (int t0 = 0; t0 < 2; ++t0) {
      const int t = tid + t0 * 512;
      const int pidx = a0 * N_NBRS + t;
      uint_t pk = 0;
      if (pidx < N_ATOMS * N_NBRS) {
        const float r = dR[pidx];
        const int  nb = nbr[pidx];
        int i0 = (int)(r * (191.0f / RCUT) + 0.5f);
        i0 = min(i0, 191);
        pk = (uint_t)i0 | ((uint_t)Z[nb] << 8);
      }
      s_pk[t] = pk;
    }
    if (tid < 32) sZ[tid] = (a0 + tid < N_ATOMS) ? Z[a0 + tid] : 0;
    __syncthreads();

    // -- cfconv for atom a0+m (invalid atoms compute garbage, masked later) --
    {
      f16x2 acc[4];
      #pragma unroll
      for (int c = 0; c < 4; ++c) acc[c] = (f16x2)0;

      uint4 twA[4], ytA[4], twB[4], ytB[4];

#define IG(BK, gi) { \
    _Pragma("unroll") \
    for (int d = 0; d < 4; ++d) { \
      const uint_t pk = s_pk[m * N_NBRS + (gi) * 4 + d]; \
      tw##BK[d] = *(const uint4*)(wb + ((pk & 0xFFu) << 8)); \
      yt##BK[d] = *(const uint4*)(yb + ((pk >> 8) << 8)); \
    } }

#define CG(BK) { \
    _Pragma("unroll") \
    for (int d = 0; d < 4; ++d) { \
      acc[0] += bch(tw##BK[d].x) * bch(yt##BK[d].x); \
      acc[1] += bch(tw##BK[d].y) * bch(yt##BK[d].y); \
      acc[2] += bch(tw##BK[d].z) * bch(yt##BK[d].z); \
      acc[3] += bch(tw##BK[d].w) * bch(yt##BK[d].w); \
    } }

      IG(A, 0) IG(B, 1)
      CG(A) IG(A, 2)
      CG(B) IG(B, 3)
      CG(A) IG(A, 4)
      CG(B) IG(B, 5)
      CG(A) IG(A, 6)
      CG(B) IG(B, 7)
      CG(A)
      CG(B)
#undef IG
#undef CG

      uint4 o;
      o.x = hcb(acc[0]); o.y = hcb(acc[1]); o.z = hcb(acc[2]); o.w = hcb(acc[3]);
      const int mm = m & 15;
      *(uint4*)&sA[m >> 4][mm * 128 + (((cq ^ mm) & 15) << 3)] = o;
    }
    __syncthreads();

    // -- dense on tile g (4-wave group), weights in registers --
    f32x4 dacc[2];
    #pragma unroll
    for (int t = 0; t < 2; ++t) dacc[t] = (f32x4){bb1[t], bb1[t], bb1[t], bb1[t]};
    #pragma unroll
    for (int k0i = 0; k0i < 4; ++k0i) {
      const f16x8 af = AFRAG(sA[g], k0i * 32);
      #pragma unroll
      for (int t = 0; t < 2; ++t)
        dacc[t] = __builtin_amdgcn_mfma_f32_16x16x32_f16(af, bw1[t][k0i], dacc[t], 0, 0, 0);
    }
    #pragma unroll
    for (int t = 0; t < 2; ++t) {
      const int c = wvg * 32 + t * 16 + rc;
      #pragma unroll
      for (int r = 0; r < 4; ++r) sB[g][swz(qk * 4 + r, c)] = (f16)ssp(dacc[t][r]);
    }
    __syncthreads();

    #pragma unroll
    for (int t = 0; t < 2; ++t) dacc[t] = (f32x4){bb2[t], bb2[t], bb2[t], bb2[t]};
    #pragma unroll
    for (int k0i = 0; k0i < 4; ++k0i) {
      const f16x8 af = AFRAG(sB[g], k0i * 32);
      #pragma unroll
      for (int t = 0; t < 2; ++t)
        dacc[t] = __builtin_amdgcn_mfma_f32_16x16x32_f16(af, bw2[t][k0i], dacc[t], 0, 0, 0);
    }
    #pragma unroll
    for (int t = 0; t < 2; ++t) {
      const int c = wvg * 32 + t * 16 + rc;
      #pragma unroll
      for (int r = 0; r < 4; ++r) {
        const int mm = qk * 4 + r;
        const float x = embed[(size_t)sZ[g * 16 + mm] * 128 + c] + dacc[t][r];
        sA[g][swz(mm, c)] = (f16)x;
      }
    }
    __syncthreads();

    // -- MLP 128 -> 64 -> 1, masked accumulate --
    f32x4 a2 = (f32x4){bm, bm, bm, bm};
    #pragma unroll
    for (int k0i = 0; k0i < 4; ++k0i)
      a2 = __builtin_amdgcn_mfma_f32_16x16x32_f16(AFRAG(sA[g], k0i * 32), bwm[k0i], a2, 0, 0, 0);
    #pragma unroll
    for (int r = 0; r < 4; ++r) {
      const int atom = a0 + g * 16 + qk * 4 + r;
      if (atom < N_ATOMS) vsum = fmaf(ssp(a2[r]), cm, vsum);
    }
  }
#undef AFRAG

  // -- block reduce -> partial --
  #pragma unroll
  for (int o = 1; o < 64; o <<= 1) vsum += __shfl_xor(vsum, o, 64);
  if (l == 0) sRed[w] = vsum;
  __syncthreads();
  if (tid == 0) {
    float s = 0.0f;
    #pragma unroll
    for (int i = 0; i < 8; ++i) s += sRed[i];
    partial[blockIdx.x] = s;
  }
}

// ---- final reduce: one block sums the partials, applies bias + scale ----
__global__ void __launch_bounds__(256, 1)
reduce_kernel(const float* __restrict__ partial,
              const float* __restrict__ mb2,
              float* __restrict__ out) {
  const int tid = threadIdx.x;
  float s = (tid < PBLOCKS) ? partial[tid] : 0.0f;
  __shared__ float sr[4];
  #pragma unroll
  for (int o = 1; o < 64; o <<= 1) s += __shfl_xor(s, o, 64);
  if ((tid & 63) == 0) sr[tid >> 6] = s;
  __syncthreads();
  if (tid == 0) {
    out[0] = 20.0f * (sr[0] + sr[1] + sr[2] + sr[3] + (float)N_ATOMS * mb2[0]);
  }
}

extern "C" void kernel_launch(void* const* d_in, const int* in_sizes, int n_in,
                              void* d_out, int out_size, void* d_ws, size_t ws_size,
                              hipStream_t stream) {
  const float* dR    = (const float*)d_in[0];
  const int*   Z     = (const int*)  d_in[1];
  const int*   nbr   = (const int*)  d_in[2];
  const float* embed = (const float*)d_in[3];
  const float* fw1   = (const float*)d_in[4];
  const float* fb1   = (const float*)d_in[5];
  const float* fw2   = (const float*)d_in[6];
  const float* fb2   = (const float*)d_in[7];
  const float* in2f  = (const float*)d_in[8];
  const float* w1    = (const float*)d_in[9];
  const float* b1    = (const float*)d_in[10];
  const float* w2    = (const float*)d_in[11];
  const float* b2    = (const float*)d_in[12];
  const float* mw1   = (const float*)d_in[13];
  const float* mb1   = (const float*)d_in[14];
  const float* mw2   = (const float*)d_in[15];
  const float* mb2   = (const float*)d_in[16];
  float* out = (float*)d_out;

  char* ws = (char*)d_ws;
  f16*   tabh    = (f16*)ws;                               // 48 KB
  f16*   ytab    = (f16*)(ws + (size_t)64 * 1024);         // 25.6 KB
  f16*   w1ht    = (f16*)(ws + (size_t)128 * 1024);        // 32 KB
  f16*   w2ht    = (f16*)(ws + (size_t)192 * 1024);        // 32 KB
  f16*   mw1ht   = (f16*)(ws + (size_t)256 * 1024);        // 16 KB
  float* partial = (float*)(ws + (size_t)384 * 1024);      // 1 KB

  prep_all_kernel<<<NTB + 64, 256, 0, stream>>>(fw1, fb1, fw2, fb2,
      w1, w2, mw1, embed, in2f, tabh, ytab, w1ht, w2ht, mw1ht);
  fused_kernel<<<PBLOCKS, 512, 0, stream>>>(dR, Z, nbr, embed,
      tabh, ytab, w1ht, b1, w2ht, b2, mw1ht, mb1, mw2, partial);
  reduce_kernel<<<1, 256, 0, stream>>>(partial, mb2, out);
}